// Round 4
// baseline (277.426 us; speedup 1.0000x reference)
//
#include <hip/hip_runtime.h>
#include <math.h>

#define N_ATOMS 20000
#define N_EDGES 200000
#define CH 64
#define NB 8
#define NK 11
#define COPY_BLOCKS 3125   // 200000*64/4 float4 / (256 threads * 4 each)

// ---------------------------------------------------------------
// Kernel 1: histogram of idx_i
__global__ __launch_bounds__(256) void hist_kernel(
    const int* __restrict__ idx_i, int* __restrict__ counts)
{
    int e = blockIdx.x * blockDim.x + threadIdx.x;
    if (e >= N_EDGES) return;
    atomicAdd(&counts[idx_i[e]], 1);
}

// ---------------------------------------------------------------
// Kernel 2: exclusive scan (single 1024-thread block)
__global__ __launch_bounds__(1024) void scan_kernel(
    const int* __restrict__ counts, int* __restrict__ offsets,
    int* __restrict__ cursor)
{
    __shared__ int part[1024];
    const int CHUNK = 20;  // 1024*20 = 20480 >= 20000
    int t = threadIdx.x;
    int beg = t * CHUNK;
    int s = 0;
    for (int k = 0; k < CHUNK; ++k) {
        int idx = beg + k;
        if (idx < N_ATOMS) s += counts[idx];
    }
    part[t] = s;
    __syncthreads();
    for (int off = 1; off < 1024; off <<= 1) {
        int v = (t >= off) ? part[t - off] : 0;
        __syncthreads();
        part[t] += v;
        __syncthreads();
    }
    int run = part[t] - s;
    for (int k = 0; k < CHUNK; ++k) {
        int idx = beg + k;
        if (idx < N_ATOMS) {
            offsets[idx] = run;
            cursor[idx] = run;
            run += counts[idx];
        }
    }
    if (t == 0) offsets[N_ATOMS] = N_EDGES;
}

// ---------------------------------------------------------------
// Kernel 3: scatter into CSR order, computing geometry on the fly
__global__ __launch_bounds__(256) void scatter_geom_kernel(
    const float* __restrict__ rij, const int* __restrict__ idx_i,
    const int* __restrict__ idx_j, int* __restrict__ cursor,
    int* __restrict__ jlist, float4* __restrict__ ge4)
{
    int e = blockIdx.x * blockDim.x + threadIdx.x;
    if (e >= N_EDGES) return;

    float rx = rij[e * 3 + 0];
    float ry = rij[e * 3 + 1];
    float rz = rij[e * 3 + 2];
    float d = sqrtf(rx * rx + ry * ry + rz * rz);
    float inv = 1.0f / (d + 1e-12f);

    float dc = fminf(d, 5.0f);
    float fcut = 0.5f * (cosf(3.14159265358979323846f * dc * 0.2f) + 1.0f);

    float rbf[NB];
#pragma unroll
    for (int b = 0; b < NB; ++b) {
        float mu = (5.0f / 7.0f) * (float)b;
        float t = d - mu;
        rbf[b] = expf(-2.0f * t * t) * fcut;
    }

    int p = atomicAdd(&cursor[idx_i[e]], 1);
    jlist[p] = idx_j[e];
    ge4[p * 3 + 0] = make_float4(rx * inv, ry * inv, rz * inv, rbf[0]);
    ge4[p * 3 + 1] = make_float4(rbf[1], rbf[2], rbf[3], rbf[4]);
    ge4[p * 3 + 2] = make_float4(rbf[5], rbf[6], rbf[7], 0.f);
}

// ---------------------------------------------------------------
// Path-split accumulation: wave WID owns a subset of coupling paths.
// WID 0: {0,4,9} -> a0      WID 1: {1,3,6,8} -> a1[0..2]
// WID 2: {2,5,7,10} x=0,1 -> a2[0..5]   WID 3: same paths x=2 -> a2[6..8]
template<int WID>
__device__ __forceinline__ void accum_loop(
    int n, int c,
    const int* __restrict__ offsets,
    const int* __restrict__ jlist, const float4* __restrict__ ge4,
    const float* __restrict__ node0, const float* __restrict__ node1,
    const float* __restrict__ node2, const float* __restrict__ rbf_w,
    float* __restrict__ abuf)
{
    constexpr int NP = (WID == 0) ? 3 : 4;
    constexpr int PTH[4][4] = {{0, 4, 9, 0}, {1, 3, 6, 8}, {2, 5, 7, 10}, {2, 5, 7, 10}};

    // per-lane weight slice: registers, statically indexed
    float wp[NP][NB];
#pragma unroll
    for (int pi = 0; pi < NP; ++pi)
#pragma unroll
        for (int b = 0; b < NB; ++b)
            wp[pi][b] = rbf_w[(PTH[WID][pi] * NB + b) * CH + c];

    float acc[(WID == 2) ? 6 : (WID == 1 || WID == 3) ? 3 : 1];
#pragma unroll
    for (int q = 0; q < (int)(sizeof(acc) / sizeof(float)); ++q) acc[q] = 0.f;

    int beg = offsets[n];
    int end = offsets[n + 1];

    // loads needed per wave
    auto LOADH = [&](int j, float& H0, float* H1, float* H2) {
        size_t b0 = (size_t)j * CH + c;
        H0 = node0[b0];
        if constexpr (WID <= 1) {
#pragma unroll
            for (int x = 0; x < 3; ++x) H1[x] = node1[b0 * 3 + x];
#pragma unroll
            for (int q = 0; q < 9; ++q) H2[q] = node2[b0 * 9 + q];
        } else if constexpr (WID == 2) {
            H1[0] = node1[b0 * 3 + 0];
            H1[1] = node1[b0 * 3 + 1];
#pragma unroll
            for (int q = 0; q < 6; ++q) H2[q] = node2[b0 * 9 + q];
        } else {
            H1[0] = node1[b0 * 3 + 2];
#pragma unroll
            for (int q = 0; q < 3; ++q) H2[q] = node2[b0 * 9 + 6 + q];
        }
    };

    float4 g0, g1, g2;
    float ch0 = 0.f, ch1[3], ch2[9];
    int jn = 0;

    if (beg < end) {
        g0 = ge4[beg * 3 + 0];
        g1 = ge4[beg * 3 + 1];
        g2 = ge4[beg * 3 + 2];
        LOADH(jlist[beg], ch0, ch1, ch2);
        jn = (beg + 1 < end) ? jlist[beg + 1] : 0;
    }

    for (int p = beg; p < end; ++p) {
        float rh[3] = {g0.x, g0.y, g0.z};
        float rbf[NB] = {g0.w, g1.x, g1.y, g1.z, g1.w, g2.x, g2.y, g2.z};
        float sh0 = ch0;
        float sh1[3], sh2[9];
#pragma unroll
        for (int x = 0; x < 3; ++x) sh1[x] = ch1[x];
#pragma unroll
        for (int q = 0; q < 9; ++q) sh2[q] = ch2[q];

        if (p + 1 < end) {
            g0 = ge4[(p + 1) * 3 + 0];
            g1 = ge4[(p + 1) * 3 + 1];
            g2 = ge4[(p + 1) * 3 + 2];
            LOADH(jn, ch0, ch1, ch2);
            jn = (p + 2 < end) ? jlist[p + 2] : 0;
        }

        float fc[NP];
#pragma unroll
        for (int pi = 0; pi < NP; ++pi) {
            float s = 0.f;
#pragma unroll
            for (int b = 0; b < NB; ++b) s = fmaf(rbf[b], wp[pi][b], s);
            fc[pi] = s;
        }

        if constexpr (WID == 0) {
            float u1 = sh1[0] * rh[0] + sh1[1] * rh[1] + sh1[2] * rh[2];
            float v2x = sh2[0] * rh[0] + sh2[1] * rh[1] + sh2[2] * rh[2];
            float v2y = sh2[3] * rh[0] + sh2[4] * rh[1] + sh2[5] * rh[2];
            float v2z = sh2[6] * rh[0] + sh2[7] * rh[1] + sh2[8] * rh[2];
            float w2 = v2x * rh[0] + v2y * rh[1] + v2z * rh[2];
            acc[0] = fmaf(fc[0], sh0, acc[0]);
            acc[0] = fmaf(fc[1], u1, acc[0]);
            acc[0] = fmaf(fc[2], w2, acc[0]);
        } else if constexpr (WID == 1) {
            float u1 = sh1[0] * rh[0] + sh1[1] * rh[1] + sh1[2] * rh[2];
            float v2[3];
#pragma unroll
            for (int x = 0; x < 3; ++x)
                v2[x] = sh2[x * 3] * rh[0] + sh2[x * 3 + 1] * rh[1] + sh2[x * 3 + 2] * rh[2];
            float t = fc[0] * sh0 + fc[2] * u1;
#pragma unroll
            for (int x = 0; x < 3; ++x)
                acc[x] += t * rh[x] + fc[1] * sh1[x] + fc[3] * v2[x];
        } else if constexpr (WID == 2) {
#pragma unroll
            for (int x = 0; x < 2; ++x) {
                float v2x = sh2[x * 3] * rh[0] + sh2[x * 3 + 1] * rh[1] + sh2[x * 3 + 2] * rh[2];
                float cx = fc[0] * sh0 * rh[x] + fc[1] * sh1[x] + fc[3] * v2x;
#pragma unroll
                for (int y = 0; y < 3; ++y)
                    acc[x * 3 + y] += cx * rh[y] + fc[2] * sh2[x * 3 + y];
            }
        } else {
            float v2z = sh2[0] * rh[0] + sh2[1] * rh[1] + sh2[2] * rh[2];
            float cx = fc[0] * sh0 * rh[2] + fc[1] * sh1[0] + fc[3] * v2z;
#pragma unroll
            for (int y = 0; y < 3; ++y)
                acc[y] += cx * rh[y] + fc[2] * sh2[y];
        }
    }

    const float SC = 0.1f;  // 1/NORM_FACTOR
    if constexpr (WID == 0) {
        abuf[c * 16 + 0] = acc[0] * SC;
    } else if constexpr (WID == 1) {
#pragma unroll
        for (int x = 0; x < 3; ++x) abuf[c * 16 + 1 + x] = acc[x] * SC;
    } else if constexpr (WID == 2) {
#pragma unroll
        for (int q = 0; q < 6; ++q) abuf[c * 16 + 4 + q] = acc[q] * SC;
    } else {
#pragma unroll
        for (int q = 0; q < 3; ++q) abuf[c * 16 + 10 + q] = acc[q] * SC;
    }
}

// ---------------------------------------------------------------
// Kernel 4: fused gather (path-split) + SI matmul + nonlinearity + residual.
// 256 threads = 4 waves per atom. Blocks >= N_ATOMS copy edge0.
__global__ __launch_bounds__(256, 4) void atom_fused_kernel(
    const float* __restrict__ node0, const float* __restrict__ node1,
    const float* __restrict__ node2,
    const int* __restrict__ jlist, const int* __restrict__ offsets,
    const float4* __restrict__ ge4, const float* __restrict__ rbf_w,
    const float* __restrict__ si_w0, const float* __restrict__ si_b0,
    const float* __restrict__ si_w1, const float* __restrict__ si_w2,
    const float* __restrict__ nl_w1, const float* __restrict__ nl_b1,
    const float* __restrict__ nl_w2, const float* __restrict__ nl_b2,
    float* __restrict__ out0, float* __restrict__ out1, float* __restrict__ out2,
    const float4* __restrict__ edge0_in, float4* __restrict__ edge0_out)
{
    int n = blockIdx.x;
    int wv = threadIdx.x >> 6;
    int c = threadIdx.x & 63;

    if (n >= N_ATOMS) {
        size_t base = (size_t)(n - N_ATOMS) * 1024;
#pragma unroll
        for (int k = 0; k < 4; ++k)
            edge0_out[base + k * 256 + threadIdx.x] = edge0_in[base + k * 256 + threadIdx.x];
        return;
    }

    __shared__ __align__(16) float abuf[CH * 16];   // [cc][16]: 0=a0, 1-3=a1, 4-12=a2
    __shared__ float pbuf[4][CH][13];

    switch (wv) {
        case 0: accum_loop<0>(n, c, offsets, jlist, ge4, node0, node1, node2, rbf_w, abuf); break;
        case 1: accum_loop<1>(n, c, offsets, jlist, ge4, node0, node1, node2, rbf_w, abuf); break;
        case 2: accum_loop<2>(n, c, offsets, jlist, ge4, node0, node1, node2, rbf_w, abuf); break;
        default: accum_loop<3>(n, c, offsets, jlist, ge4, node0, node1, node2, rbf_w, abuf); break;
    }
    __syncthreads();

    // ---- SI mixing, cc-split: wave wv reduces input channels [16wv, 16wv+16) ----
    float ps[13];
#pragma unroll
    for (int k = 0; k < 13; ++k) ps[k] = 0.f;

    for (int t = 0; t < 16; ++t) {
        int cc = wv * 16 + t;
        const float* ar = &abuf[cc * 16];
        float4 A0 = *(const float4*)(ar + 0);
        float4 A1 = *(const float4*)(ar + 4);
        float4 A2 = *(const float4*)(ar + 8);
        float  A3 = ar[12];
        float w0v = si_w0[cc * CH + c];
        float w1v = si_w1[cc * CH + c];
        float w2v = si_w2[cc * CH + c];
        ps[0] = fmaf(A0.x, w0v, ps[0]);
        ps[1] = fmaf(A0.y, w1v, ps[1]);
        ps[2] = fmaf(A0.z, w1v, ps[2]);
        ps[3] = fmaf(A0.w, w1v, ps[3]);
        ps[4] = fmaf(A1.x, w2v, ps[4]);
        ps[5] = fmaf(A1.y, w2v, ps[5]);
        ps[6] = fmaf(A1.z, w2v, ps[6]);
        ps[7] = fmaf(A1.w, w2v, ps[7]);
        ps[8] = fmaf(A2.x, w2v, ps[8]);
        ps[9] = fmaf(A2.y, w2v, ps[9]);
        ps[10] = fmaf(A2.z, w2v, ps[10]);
        ps[11] = fmaf(A2.w, w2v, ps[11]);
        ps[12] = fmaf(A3, w2v, ps[12]);
    }
#pragma unroll
    for (int k = 0; k < 13; ++k) pbuf[wv][c][k] = ps[k];
    __syncthreads();

    // ---- finalize: wave 0 -> way0+way1, wave 1 -> way2 ----
    if (wv == 0) {
        float s0 = si_b0[c];
        float s1[3] = {0.f, 0.f, 0.f};
#pragma unroll
        for (int w = 0; w < 4; ++w) {
            s0 += pbuf[w][c][0];
#pragma unroll
            for (int x = 0; x < 3; ++x) s1[x] += pbuf[w][c][1 + x];
        }
        float r0 = s0 / (1.0f + expf(-s0));
        out0[(size_t)n * CH + c] = node0[(size_t)n * CH + c] + r0;

        float n1 = sqrtf(s1[0] * s1[0] + s1[1] * s1[1] + s1[2] * s1[2] + 1e-6f);
        float g1 = n1 * nl_w1[c] + nl_b1[c];
        float gate1 = g1 / (1.0f + expf(-g1));
#pragma unroll
        for (int x = 0; x < 3; ++x)
            out1[((size_t)n * CH + c) * 3 + x] =
                node1[((size_t)n * CH + c) * 3 + x] + s1[x] * gate1;
    } else if (wv == 1) {
        float s2[9];
#pragma unroll
        for (int q = 0; q < 9; ++q) s2[q] = 0.f;
#pragma unroll
        for (int w = 0; w < 4; ++w)
#pragma unroll
            for (int q = 0; q < 9; ++q) s2[q] += pbuf[w][c][4 + q];

        float n2sq = 1e-6f;
#pragma unroll
        for (int q = 0; q < 9; ++q) n2sq = fmaf(s2[q], s2[q], n2sq);
        float n2 = sqrtf(n2sq);
        float g2 = n2 * nl_w2[c] + nl_b2[c];
        float gate2 = g2 / (1.0f + expf(-g2));
#pragma unroll
        for (int q = 0; q < 9; ++q)
            out2[((size_t)n * CH + c) * 9 + q] =
                node2[((size_t)n * CH + c) * 9 + q] + s2[q] * gate2;
    }
}

extern "C" void kernel_launch(void* const* d_in, const int* in_sizes, int n_in,
                              void* d_out, int out_size, void* d_ws, size_t ws_size,
                              hipStream_t stream) {
    const float* node0 = (const float*)d_in[0];
    const float* node1 = (const float*)d_in[1];
    const float* node2 = (const float*)d_in[2];
    const float* edge0 = (const float*)d_in[3];
    const float* rij   = (const float*)d_in[4];
    const int*   idx_i = (const int*)d_in[5];
    const int*   idx_j = (const int*)d_in[6];
    const float* rbf_w = (const float*)d_in[7];
    const float* si_w0 = (const float*)d_in[8];
    const float* si_b0 = (const float*)d_in[9];
    const float* si_w1 = (const float*)d_in[10];
    const float* si_w2 = (const float*)d_in[11];
    const float* nl_w1 = (const float*)d_in[12];
    const float* nl_b1 = (const float*)d_in[13];
    const float* nl_w2 = (const float*)d_in[14];
    const float* nl_b2 = (const float*)d_in[15];

    float* out = (float*)d_out;
    float* out0 = out;                                   // [A, C]
    float* out1 = out + (size_t)N_ATOMS * CH;            // [A, C, 3]
    float* out2 = out1 + (size_t)N_ATOMS * CH * 3;       // [A, C, 3, 3]
    float* oute = out2 + (size_t)N_ATOMS * CH * 9;       // [E, C]

    // workspace layout
    char* ws = (char*)d_ws;
    int* counts  = (int*)ws;                              ws += N_ATOMS * sizeof(int);
    int* cursor  = (int*)ws;                              ws += N_ATOMS * sizeof(int);
    int* offsets = (int*)ws;                              ws += (N_ATOMS + 1) * sizeof(int);
    ws = (char*)(((size_t)ws + 15) & ~(size_t)15);
    int* jlist   = (int*)ws;                              ws += N_EDGES * sizeof(int);
    ws = (char*)(((size_t)ws + 15) & ~(size_t)15);
    float4* ge4  = (float4*)ws;                           // 3 * N_EDGES float4

    hipMemsetAsync(counts, 0, N_ATOMS * sizeof(int), stream);

    hist_kernel<<<(N_EDGES + 255) / 256, 256, 0, stream>>>(idx_i, counts);

    scan_kernel<<<1, 1024, 0, stream>>>(counts, offsets, cursor);

    scatter_geom_kernel<<<(N_EDGES + 255) / 256, 256, 0, stream>>>(
        rij, idx_i, idx_j, cursor, jlist, ge4);

    atom_fused_kernel<<<N_ATOMS + COPY_BLOCKS, 256, 0, stream>>>(
        node0, node1, node2, jlist, offsets, ge4, rbf_w,
        si_w0, si_b0, si_w1, si_w2, nl_w1, nl_b1, nl_w2, nl_b2,
        out0, out1, out2,
        (const float4*)edge0, (float4*)oute);
}